// Round 1
// baseline (1698.619 us; speedup 1.0000x reference)
//
#include <hip/hip_runtime.h>

// Problem constants
#define B_N 16384
#define D_K 512
#define C_N 1000
#define M_N 8

// Tiling
#define TM 128   // rows per block
#define TN 128   // cols per block
#define TK 32    // k-step
#define CT 8     // ceil(C_N / TN) = 8 (covers 1024 cols, cols >= 1000 masked)

__global__ __launch_bounds__(256) void ve_zero_out(float* __restrict__ out, int n4) {
    int i = blockIdx.x * blockDim.x + threadIdx.x;
    const float4 z = make_float4(0.f, 0.f, 0.f, 0.f);
    for (; i < n4; i += gridDim.x * blockDim.x)
        reinterpret_cast<float4*>(out)[i] = z;
}

// One block computes a 128x128 logits tile for model m, then reduces to a
// per-row (max, argmax) partial for this C-tile, written to ws.
__global__ __launch_bounds__(256) void ve_gemm_argmax(
    const float* __restrict__ x,     // [B_N, D_K]
    const float* __restrict__ W,     // [M_N, D_K, C_N]
    const float* __restrict__ bias,  // [M_N, C_N]
    float2* __restrict__ part)       // [M_N, B_N, CT] (val, idx-as-float)
{
    __shared__ float xs[TK][TM + 1];  // [k][row], +1 pad
    __shared__ float ws[TK][TN];      // [k][col]

    const int ct = blockIdx.x;   // 0..7  C-tile
    const int rt = blockIdx.y;   // 0..127 row-tile
    const int m  = blockIdx.z;   // 0..7  model
    const int tid = threadIdx.x;
    const int tx = tid & 15;     // col lane
    const int ty = tid >> 4;     // row lane
    const int r0 = rt * TM;
    const int c0 = ct * TN;

    float acc[8][8];
#pragma unroll
    for (int i = 0; i < 8; i++)
#pragma unroll
        for (int j = 0; j < 8; j++) acc[i][j] = 0.f;

    const float* xbase = x + (size_t)r0 * D_K;

    for (int kt = 0; kt < D_K; kt += TK) {
        // ---- stage x tile: 128 rows x 32 k  (transpose into xs[k][row]) ----
#pragma unroll
        for (int i = 0; i < 4; i++) {
            int l   = tid + i * 256;
            int row = l >> 3;      // 0..127
            int kq  = l & 7;       // float4 slot within the 32-k strip
            float4 v = *reinterpret_cast<const float4*>(xbase + (size_t)row * D_K + kt + kq * 4);
            int kk = kq * 4;
            xs[kk + 0][row] = v.x;
            xs[kk + 1][row] = v.y;
            xs[kk + 2][row] = v.z;
            xs[kk + 3][row] = v.w;
        }
        // ---- stage W tile: 32 k x 128 cols (already [k][c] layout) ----
#pragma unroll
        for (int i = 0; i < 4; i++) {
            int l  = tid + i * 256;
            int kk = l >> 5;       // 0..31
            int cq = l & 31;       // float4 slot across 128 cols
            int c  = c0 + cq * 4;
            const float* p = W + ((size_t)(m * D_K + kt + kk)) * C_N + c;
            float4 v;
            if (c + 3 < C_N) {
                v = *reinterpret_cast<const float4*>(p);
            } else {
                v.x = (c + 0 < C_N) ? p[0] : 0.f;
                v.y = (c + 1 < C_N) ? p[1] : 0.f;
                v.z = (c + 2 < C_N) ? p[2] : 0.f;
                v.w = (c + 3 < C_N) ? p[3] : 0.f;
            }
            ws[kk][cq * 4 + 0] = v.x;
            ws[kk][cq * 4 + 1] = v.y;
            ws[kk][cq * 4 + 2] = v.z;
            ws[kk][cq * 4 + 3] = v.w;
        }
        __syncthreads();

        for (int kk = 0; kk < TK; kk++) {
            float a[8], bb[8];
#pragma unroll
            for (int i = 0; i < 8; i++) a[i] = xs[kk][ty + i * 16];
#pragma unroll
            for (int j = 0; j < 8; j++) bb[j] = ws[kk][tx + j * 16];
#pragma unroll
            for (int i = 0; i < 8; i++)
#pragma unroll
                for (int j = 0; j < 8; j++) acc[i][j] += a[i] * bb[j];
        }
        __syncthreads();
    }

    // ---- bias + per-C-tile argmax ----
    const float NEG_INF = -__builtin_huge_valf();
    float bv[8];
    int   cv[8];
#pragma unroll
    for (int j = 0; j < 8; j++) {
        int c = c0 + tx + j * 16;
        cv[j] = c;
        bv[j] = (c < C_N) ? bias[m * C_N + c] : 0.f;
    }

#pragma unroll
    for (int i = 0; i < 8; i++) {
        int r = r0 + ty + i * 16;
        float best = NEG_INF;
        int bidx = 0x7fffffff;
#pragma unroll
        for (int j = 0; j < 8; j++) {
            int c = cv[j];
            float v = (c < C_N) ? (acc[i][j] + bv[j]) : NEG_INF;
            if (v > best || (v == best && c < bidx)) { best = v; bidx = c; }
        }
        // butterfly reduce across the 16 column-lanes (same ty group)
#pragma unroll
        for (int mask = 1; mask < 16; mask <<= 1) {
            float ov = __shfl_xor(best, mask);
            int   oi = __shfl_xor(bidx, mask);
            if (ov > best || (ov == best && oi < bidx)) { best = ov; bidx = oi; }
        }
        if (tx == 0) {
            part[((size_t)m * B_N + r) * CT + ct] = make_float2(best, __int_as_float(bidx));
        }
    }
}

// One thread per row: reduce the CT partials per model, then deterministic
// in-thread weighted vote accumulation (row is owned by this thread).
__global__ __launch_bounds__(256) void ve_vote(
    const float2* __restrict__ part,   // [M_N, B_N, CT]
    const float* __restrict__ coefs,   // [M_N]
    float* __restrict__ out)           // [B_N, C_N]
{
    int r = blockIdx.x * blockDim.x + threadIdx.x;
    if (r >= B_N) return;
    const float NEG_INF = -__builtin_huge_valf();
#pragma unroll
    for (int m = 0; m < M_N; m++) {
        float best = NEG_INF;
        int bidx = 0x7fffffff;
#pragma unroll
        for (int ct = 0; ct < CT; ct++) {
            float2 p = part[((size_t)m * B_N + r) * CT + ct];
            int oi = __float_as_int(p.y);
            if (p.x > best || (p.x == best && oi < bidx)) { best = p.x; bidx = oi; }
        }
        out[(size_t)r * C_N + bidx] += coefs[m] * 0.125f;
    }
}

extern "C" void kernel_launch(void* const* d_in, const int* in_sizes, int n_in,
                              void* d_out, int out_size, void* d_ws, size_t ws_size,
                              hipStream_t stream) {
    const float* x     = (const float*)d_in[0];  // [16384, 512]
    const float* W     = (const float*)d_in[1];  // [8, 512, 1000]
    const float* bias  = (const float*)d_in[2];  // [8, 1000]
    const float* coefs = (const float*)d_in[3];  // [8]
    float* out = (float*)d_out;                  // [16384, 1000]
    float2* part = (float2*)d_ws;                // needs M*B*CT*8 = 8.4 MB

    ve_zero_out<<<2048, 256, 0, stream>>>(out, (B_N * C_N) / 4);

    dim3 grid(CT, B_N / TM, M_N);  // 8 x 128 x 8 = 8192 blocks
    ve_gemm_argmax<<<grid, 256, 0, stream>>>(x, W, bias, part);

    ve_vote<<<(B_N + 255) / 256, 256, 0, stream>>>(part, coefs, out);
}

// Round 2
// 697.126 us; speedup vs baseline: 2.4366x; 2.4366x over previous
//
#include <hip/hip_runtime.h>

#define B_N 16384
#define D_K 512
#define C_N 1000
#define CP 1024
#define M_N 8
#define GAP_EPS 2e-4f

typedef __attribute__((ext_vector_type(8))) short bf16x8;
typedef __attribute__((ext_vector_type(4))) float f32x4;

typedef const __attribute__((address_space(1))) unsigned int* gptr_t;
typedef __attribute__((address_space(3))) unsigned int* lptr_t;

__device__ __forceinline__ void gload16(const void* g, void* l) {
    __builtin_amdgcn_global_load_lds((gptr_t)g, (lptr_t)l, 16, 0, 0);
}

__device__ __forceinline__ unsigned short bf16_rn(float f) {
    unsigned u = __float_as_uint(f);
    unsigned lsb = (u >> 16) & 1u;
    u += 0x7FFFu + lsb;
    return (unsigned short)(u >> 16);
}

// f = hi + lo: hi = truncated-to-bf16, lo = RN-bf16(remainder). Exact fp32 subtraction.
__device__ __forceinline__ void split2(float f, unsigned short& h, unsigned short& l) {
    unsigned u = __float_as_uint(f) & 0xFFFF0000u;
    h = (unsigned short)(u >> 16);
    float r = f - __uint_as_float(u);
    l = bf16_rn(r);
}

// ---------------- conversion kernels ----------------

__global__ __launch_bounds__(256) void ve_conv_x(const float* __restrict__ x,
        unsigned short* __restrict__ xh, unsigned short* __restrict__ xl,
        unsigned int* __restrict__ cnt) {
    int i = blockIdx.x * 256 + threadIdx.x;   // one float4 per thread, grid exact
    if (i == 0) *cnt = 0u;
    float4 v = reinterpret_cast<const float4*>(x)[i];
    ushort4 h, l;
    split2(v.x, h.x, l.x); split2(v.y, h.y, l.y);
    split2(v.z, h.z, l.z); split2(v.w, h.w, l.w);
    reinterpret_cast<ushort4*>(xh)[i] = h;
    reinterpret_cast<ushort4*>(xl)[i] = l;
}

// W [8][512][1000] fp32 -> WhT/WlT [8][1024][512] bf16 (transposed, c-padded with 0)
__global__ __launch_bounds__(256) void ve_conv_w(const float* __restrict__ W,
        unsigned short* __restrict__ wht, unsigned short* __restrict__ wlt) {
    __shared__ float t[64][65];
    const int m = blockIdx.z, k0 = blockIdx.y * 64, c0 = blockIdx.x * 64;
    const int tid = threadIdx.x;
#pragma unroll
    for (int p = 0; p < 16; ++p) {
        int idx = p * 256 + tid;
        int kk = idx >> 6, cc = idx & 63;
        int c = c0 + cc;
        t[kk][cc] = (c < C_N) ? W[((size_t)m * D_K + k0 + kk) * C_N + c] : 0.f;
    }
    __syncthreads();
#pragma unroll
    for (int p = 0; p < 4; ++p) {
        int idx = p * 256 + tid;
        int cc = idx >> 4, kq = idx & 15;
        ushort4 h, l;
        split2(t[kq * 4 + 0][cc], h.x, l.x);
        split2(t[kq * 4 + 1][cc], h.y, l.y);
        split2(t[kq * 4 + 2][cc], h.z, l.z);
        split2(t[kq * 4 + 3][cc], h.w, l.w);
        size_t o = ((size_t)m * CP + c0 + cc) * D_K + k0 + kq * 4;
        *reinterpret_cast<ushort4*>(wht + o) = h;
        *reinterpret_cast<ushort4*>(wlt + o) = l;
    }
}

// ---------------- split-bf16 MFMA GEMM + per-row global top-2 ----------------
// One block per (m, 128-row tile); loops over all 8 column tiles of CP=1024.
// LDS tile row layout (128 B): [ hi-plane k0..31 | lo-plane k0..31 ], 16B slots
// XOR-swizzled by (row&7); swizzle pre-applied on the global source address.

__global__ __launch_bounds__(256, 2) void ve_gemm_top2(
        const unsigned short* __restrict__ Xh, const unsigned short* __restrict__ Xl,
        const unsigned short* __restrict__ WhT, const unsigned short* __restrict__ WlT,
        const float* __restrict__ bias, float4* __restrict__ part) {
    __shared__ unsigned short At[128 * 64];
    __shared__ unsigned short Bt[128 * 64];
    __shared__ float4 wtop[128][2];
    __shared__ float4 run[128];
    __shared__ float bs[CP];

    const int tid = threadIdx.x;
    const int lane = tid & 63;
    const int w = tid >> 6;
    const int wr = w >> 1, wc = w & 1;
    const int m = blockIdx.y;
    const int r0 = blockIdx.x * 128;

    for (int i = tid; i < CP; i += 256) bs[i] = (i < C_N) ? bias[m * C_N + i] : -1e30f;
    if (tid < 128) run[tid] = make_float4(-1e30f, 0.f, -1e30f, 0.f);
    __syncthreads();

    const int srow = w * 8 + (lane >> 3);  // + i*32 per issue
    const int sslot = lane & 7;
    const int kg = lane >> 4;

    for (int ct = 0; ct < 8; ++ct) {
        const int c0 = ct * 128;
        f32x4 acc[4][4];
#pragma unroll
        for (int i = 0; i < 4; ++i)
#pragma unroll
            for (int j = 0; j < 4; ++j) acc[i][j] = (f32x4){0.f, 0.f, 0.f, 0.f};

        for (int kt = 0; kt < D_K; kt += 32) {
            // stage A (rows of x) and B (cols via WT), hi+lo planes together
#pragma unroll
            for (int i = 0; i < 4; ++i) {
                int row = i * 32 + srow;
                int ls = sslot ^ (row & 7);
                const unsigned short* g = ((ls & 4) ? Xl : Xh)
                        + ((size_t)(r0 + row)) * D_K + kt + (ls & 3) * 8;
                gload16(g, At + i * 2048 + w * 512);
            }
#pragma unroll
            for (int i = 0; i < 4; ++i) {
                int col = i * 32 + srow;
                int ls = sslot ^ (col & 7);
                const unsigned short* g = ((ls & 4) ? WlT : WhT)
                        + ((size_t)(m * CP + c0 + col)) * D_K + kt + (ls & 3) * 8;
                gload16(g, Bt + i * 2048 + w * 512);
            }
            __syncthreads();

            bf16x8 ah[4], al[4], bh[4], bl[4];
#pragma unroll
            for (int i = 0; i < 4; ++i) {
                int row = wr * 64 + i * 16 + (lane & 15);
                ah[i] = *reinterpret_cast<const bf16x8*>(At + row * 64 + ((kg) ^ (row & 7)) * 8);
                al[i] = *reinterpret_cast<const bf16x8*>(At + row * 64 + ((4 + kg) ^ (row & 7)) * 8);
                int col = wc * 64 + i * 16 + (lane & 15);
                bh[i] = *reinterpret_cast<const bf16x8*>(Bt + col * 64 + ((kg) ^ (col & 7)) * 8);
                bl[i] = *reinterpret_cast<const bf16x8*>(Bt + col * 64 + ((4 + kg) ^ (col & 7)) * 8);
            }
#pragma unroll
            for (int i = 0; i < 4; ++i)
#pragma unroll
                for (int j = 0; j < 4; ++j) {
                    acc[i][j] = __builtin_amdgcn_mfma_f32_16x16x32_bf16(ah[i], bh[j], acc[i][j], 0, 0, 0);
                    acc[i][j] = __builtin_amdgcn_mfma_f32_16x16x32_bf16(ah[i], bl[j], acc[i][j], 0, 0, 0);
                    acc[i][j] = __builtin_amdgcn_mfma_f32_16x16x32_bf16(al[i], bh[j], acc[i][j], 0, 0, 0);
                }
            __syncthreads();
        }

        // epilogue: bias + per-row top-2 over this 128-col tile
        const int cb = c0 + wc * 64 + (lane & 15);
        float b4[4] = {bs[cb], bs[cb + 16], bs[cb + 32], bs[cb + 48]};
#pragma unroll
        for (int i = 0; i < 4; ++i) {
#pragma unroll
            for (int reg = 0; reg < 4; ++reg) {
                float v1 = acc[i][0][reg] + b4[0]; int i1 = cb;
                float v2 = -1e30f; int i2 = 0x7fffffff;
#pragma unroll
                for (int j = 1; j < 4; ++j) {
                    float v = acc[i][j][reg] + b4[j]; int c = cb + j * 16;
                    if (v > v1 || (v == v1 && c < i1)) { v2 = v1; i2 = i1; v1 = v; i1 = c; }
                    else if (v > v2 || (v == v2 && c < i2)) { v2 = v; i2 = c; }
                }
#pragma unroll
                for (int mask = 1; mask < 16; mask <<= 1) {
                    float ov1 = __shfl_xor(v1, mask); int oi1 = __shfl_xor(i1, mask);
                    float ov2 = __shfl_xor(v2, mask); int oi2 = __shfl_xor(i2, mask);
                    if (ov1 > v1 || (ov1 == v1 && oi1 < i1)) {
                        float nv2 = v1; int ni2 = i1;
                        if (ov2 > nv2 || (ov2 == nv2 && oi2 < ni2)) { nv2 = ov2; ni2 = oi2; }
                        v1 = ov1; i1 = oi1; v2 = nv2; i2 = ni2;
                    } else if (ov1 > v2 || (ov1 == v2 && oi1 < i2)) { v2 = ov1; i2 = oi1; }
                }
                if ((lane & 15) == 0) {
                    int row = wr * 64 + i * 16 + (lane >> 4) * 4 + reg;
                    wtop[row][wc] = make_float4(v1, __int_as_float(i1), v2, __int_as_float(i2));
                }
            }
        }
        __syncthreads();
        if (tid < 128) {
            float4 rr = run[tid];
            float v1 = rr.x; int i1 = __float_as_int(rr.y);
            float v2 = rr.z; int i2 = __float_as_int(rr.w);
#pragma unroll
            for (int s = 0; s < 2; ++s) {
                float4 o = wtop[tid][s];
                float ov1 = o.x; int oi1 = __float_as_int(o.y);
                float ov2 = o.z; int oi2 = __float_as_int(o.w);
                if (ov1 > v1 || (ov1 == v1 && oi1 < i1)) {
                    float nv2 = v1; int ni2 = i1;
                    if (ov2 > nv2 || (ov2 == nv2 && oi2 < ni2)) { nv2 = ov2; ni2 = oi2; }
                    v1 = ov1; i1 = oi1; v2 = nv2; i2 = ni2;
                } else if (ov1 > v2 || (ov1 == v2 && oi1 < i2)) { v2 = ov1; i2 = oi1; }
            }
            run[tid] = make_float4(v1, __int_as_float(i1), v2, __int_as_float(i2));
        }
        __syncthreads();
    }
    if (tid < 128) part[(size_t)m * B_N + r0 + tid] = run[tid];
}

// ---------------- uncertainty flag + exact recompute + vote ----------------

__global__ __launch_bounds__(256) void ve_flag(const float4* __restrict__ part,
        unsigned int* __restrict__ wout, unsigned int* __restrict__ list,
        unsigned int* __restrict__ cnt) {
    int r = blockIdx.x * 256 + threadIdx.x;
#pragma unroll
    for (int m = 0; m < M_N; ++m) {
        float4 p = part[(size_t)m * B_N + r];
        wout[m * B_N + r] = (unsigned)__float_as_int(p.y);
        if (p.x - p.z <= GAP_EPS) {
            unsigned pos = atomicAdd(cnt, 1u);
            list[pos] = (unsigned)(m * B_N + r);
        }
    }
}

// Full exact fp32 serial-FMA argmax over all 1000 classes for flagged rows.
// Identical accumulation semantics to the (numpy-matching) fp32 baseline.
__global__ __launch_bounds__(256) void ve_exact(const float* __restrict__ x,
        const float* __restrict__ W, const float* __restrict__ bias,
        const unsigned int* __restrict__ list, const unsigned int* __restrict__ cnt,
        unsigned int* __restrict__ wout) {
    __shared__ float xs[D_K];
    __shared__ float rv[4];
    __shared__ int ri[4];
    const int tid = threadIdx.x;
    const int lane = tid & 63, wv = tid >> 6;
    const unsigned n = *cnt;
    for (unsigned u = blockIdx.x; u < n; u += gridDim.x) {
        unsigned e = list[u];
        int m = (int)(e >> 14), r = (int)(e & (B_N - 1));
        __syncthreads();
        for (int i = tid; i < D_K; i += 256) xs[i] = x[(size_t)r * D_K + i];
        __syncthreads();
        float a0 = 0.f, a1 = 0.f, a2 = 0.f, a3 = 0.f;
        const int g3 = (tid < C_N - 768);
        const int c3 = g3 ? tid + 768 : tid;
        const float* wb = W + (size_t)m * D_K * C_N;
        for (int k = 0; k < D_K; ++k) {
            float xv = xs[k];
            const float* wr_ = wb + (size_t)k * C_N;
            a0 = fmaf(xv, wr_[tid], a0);
            a1 = fmaf(xv, wr_[tid + 256], a1);
            a2 = fmaf(xv, wr_[tid + 512], a2);
            a3 = fmaf(xv, wr_[c3], a3);
        }
        const float* bb = bias + m * C_N;
        float best = a0 + bb[tid]; int bi = tid;
        float v = a1 + bb[tid + 256]; if (v > best) { best = v; bi = tid + 256; }
        v = a2 + bb[tid + 512]; if (v > best) { best = v; bi = tid + 512; }
        if (g3) { v = a3 + bb[tid + 768]; if (v > best) { best = v; bi = tid + 768; } }
#pragma unroll
        for (int mask = 1; mask < 64; mask <<= 1) {
            float ov = __shfl_xor(best, mask); int oi = __shfl_xor(bi, mask);
            if (ov > best || (ov == best && oi < bi)) { best = ov; bi = oi; }
        }
        if (lane == 0) { rv[wv] = best; ri[wv] = bi; }
        __syncthreads();
        if (tid == 0) {
            for (int q = 1; q < 4; ++q)
                if (rv[q] > best || (rv[q] == best && ri[q] < bi)) { best = rv[q]; bi = ri[q]; }
            wout[e] = (unsigned)bi;
        }
    }
}

__global__ __launch_bounds__(256) void ve_zero_out(float* __restrict__ out, int n4) {
    int i = blockIdx.x * blockDim.x + threadIdx.x;
    const float4 z = make_float4(0.f, 0.f, 0.f, 0.f);
    for (; i < n4; i += gridDim.x * blockDim.x)
        reinterpret_cast<float4*>(out)[i] = z;
}

__global__ __launch_bounds__(256) void ve_vote2(const unsigned int* __restrict__ wout,
        const float* __restrict__ coefs, float* __restrict__ out) {
    int r = blockIdx.x * 256 + threadIdx.x;
#pragma unroll
    for (int m = 0; m < M_N; ++m)
        out[(size_t)r * C_N + wout[m * B_N + r]] += coefs[m] * 0.125f;
}

// ================= fallback: proven round-1 fp32 path =================

#define TM 128
#define TN 128
#define TK 32
#define CT 8

__global__ __launch_bounds__(256) void ve_gemm_argmax_fb(
        const float* __restrict__ x, const float* __restrict__ W,
        const float* __restrict__ bias, float2* __restrict__ part) {
    __shared__ float xs[TK][TM + 1];
    __shared__ float ws[TK][TN];
    const int ct = blockIdx.x, rt = blockIdx.y, m = blockIdx.z;
    const int tid = threadIdx.x;
    const int tx = tid & 15, ty = tid >> 4;
    const int r0 = rt * TM, c0 = ct * TN;
    float acc[8][8];
#pragma unroll
    for (int i = 0; i < 8; i++)
#pragma unroll
        for (int j = 0; j < 8; j++) acc[i][j] = 0.f;
    const float* xbase = x + (size_t)r0 * D_K;
    for (int kt = 0; kt < D_K; kt += TK) {
#pragma unroll
        for (int i = 0; i < 4; i++) {
            int l = tid + i * 256;
            int row = l >> 3, kq = l & 7;
            float4 v = *reinterpret_cast<const float4*>(xbase + (size_t)row * D_K + kt + kq * 4);
            int kk = kq * 4;
            xs[kk + 0][row] = v.x; xs[kk + 1][row] = v.y;
            xs[kk + 2][row] = v.z; xs[kk + 3][row] = v.w;
        }
#pragma unroll
        for (int i = 0; i < 4; i++) {
            int l = tid + i * 256;
            int kk = l >> 5, cq = l & 31;
            int c = c0 + cq * 4;
            const float* p = W + ((size_t)(m * D_K + kt + kk)) * C_N + c;
            float4 v;
            if (c + 3 < C_N) v = *reinterpret_cast<const float4*>(p);
            else {
                v.x = (c + 0 < C_N) ? p[0] : 0.f; v.y = (c + 1 < C_N) ? p[1] : 0.f;
                v.z = (c + 2 < C_N) ? p[2] : 0.f; v.w = (c + 3 < C_N) ? p[3] : 0.f;
            }
            ws[kk][cq * 4 + 0] = v.x; ws[kk][cq * 4 + 1] = v.y;
            ws[kk][cq * 4 + 2] = v.z; ws[kk][cq * 4 + 3] = v.w;
        }
        __syncthreads();
        for (int kk = 0; kk < TK; kk++) {
            float a[8], bb[8];
#pragma unroll
            for (int i = 0; i < 8; i++) a[i] = xs[kk][ty + i * 16];
#pragma unroll
            for (int j = 0; j < 8; j++) bb[j] = ws[kk][tx + j * 16];
#pragma unroll
            for (int i = 0; i < 8; i++)
#pragma unroll
                for (int j = 0; j < 8; j++) acc[i][j] += a[i] * bb[j];
        }
        __syncthreads();
    }
    const float NEG_INF = -__builtin_huge_valf();
    float bv[8]; int cv[8];
#pragma unroll
    for (int j = 0; j < 8; j++) {
        int c = c0 + tx + j * 16;
        cv[j] = c;
        bv[j] = (c < C_N) ? bias[m * C_N + c] : 0.f;
    }
#pragma unroll
    for (int i = 0; i < 8; i++) {
        int r = r0 + ty + i * 16;
        float best = NEG_INF; int bidx = 0x7fffffff;
#pragma unroll
        for (int j = 0; j < 8; j++) {
            int c = cv[j];
            float v = (c < C_N) ? (acc[i][j] + bv[j]) : NEG_INF;
            if (v > best || (v == best && c < bidx)) { best = v; bidx = c; }
        }
#pragma unroll
        for (int mask = 1; mask < 16; mask <<= 1) {
            float ov = __shfl_xor(best, mask);
            int oi = __shfl_xor(bidx, mask);
            if (ov > best || (ov == best && oi < bidx)) { best = ov; bidx = oi; }
        }
        if (tx == 0) part[((size_t)m * B_N + r) * CT + ct] = make_float2(best, __int_as_float(bidx));
    }
}

__global__ __launch_bounds__(256) void ve_vote_fb(const float2* __restrict__ part,
        const float* __restrict__ coefs, float* __restrict__ out) {
    int r = blockIdx.x * blockDim.x + threadIdx.x;
    if (r >= B_N) return;
    const float NEG_INF = -__builtin_huge_valf();
#pragma unroll
    for (int m = 0; m < M_N; m++) {
        float best = NEG_INF; int bidx = 0x7fffffff;
#pragma unroll
        for (int ct = 0; ct < CT; ct++) {
            float2 p = part[((size_t)m * B_N + r) * CT + ct];
            int oi = __float_as_int(p.y);
            if (p.x > best || (p.x == best && oi < bidx)) { best = p.x; bidx = oi; }
        }
        out[(size_t)r * C_N + bidx] += coefs[m] * 0.125f;
    }
}

// ================= launcher =================

extern "C" void kernel_launch(void* const* d_in, const int* in_sizes, int n_in,
                              void* d_out, int out_size, void* d_ws, size_t ws_size,
                              hipStream_t stream) {
    const float* x     = (const float*)d_in[0];
    const float* W     = (const float*)d_in[1];
    const float* bias  = (const float*)d_in[2];
    const float* coefs = (const float*)d_in[3];
    float* out = (float*)d_out;

    const size_t NEED = 52ull << 20;
    if (ws_size >= NEED) {
        char* ws = (char*)d_ws;
        float4*         part = (float4*)(ws);
        unsigned int*   wout = (unsigned int*)(ws + (2ull << 20));
        unsigned int*   list = (unsigned int*)(ws + (2ull << 20) + (512ull << 10));
        unsigned int*   cnt  = (unsigned int*)(ws + (3ull << 20));
        unsigned short* Xh   = (unsigned short*)(ws + (4ull << 20));
        unsigned short* Xl   = (unsigned short*)(ws + (20ull << 20));
        unsigned short* WhT  = (unsigned short*)(ws + (36ull << 20));
        unsigned short* WlT  = (unsigned short*)(ws + (44ull << 20));

        ve_conv_x<<<8192, 256, 0, stream>>>(x, Xh, Xl, cnt);
        ve_conv_w<<<dim3(16, 8, 8), 256, 0, stream>>>(W, WhT, WlT);
        ve_gemm_top2<<<dim3(128, 8), 256, 0, stream>>>(Xh, Xl, WhT, WlT, bias, part);
        ve_flag<<<64, 256, 0, stream>>>(part, wout, list, cnt);
        ve_exact<<<128, 256, 0, stream>>>(x, W, bias, list, cnt, wout);
        ve_zero_out<<<2048, 256, 0, stream>>>(out, B_N * C_N / 4);
        ve_vote2<<<64, 256, 0, stream>>>(wout, coefs, out);
    } else {
        float2* part = (float2*)d_ws;  // 8 MiB, proven to fit
        ve_zero_out<<<2048, 256, 0, stream>>>(out, B_N * C_N / 4);
        dim3 grid(CT, B_N / TM, M_N);
        ve_gemm_argmax_fb<<<grid, 256, 0, stream>>>(x, W, bias, part);
        ve_vote_fb<<<(B_N + 255) / 256, 256, 0, stream>>>(part, coefs, out);
    }
}